// Round 6
// baseline (217.892 us; speedup 1.0000x reference)
//
#include <hip/hip_runtime.h>
#include <hip/hip_bf16.h>

#define N_ROWS 4096
#define C_CLS  1000
#define C_PAD  1024
#define A_DIM  2048

typedef __attribute__((ext_vector_type(8))) short short8;
typedef __attribute__((ext_vector_type(4))) float f32x4;

__device__ __forceinline__ unsigned short f2bf(float x) {
    unsigned u = __float_as_uint(x);
    unsigned rounding = 0x7fffu + ((u >> 16) & 1u);
    return (unsigned short)((u + rounding) >> 16);
}

__device__ __forceinline__ float bf2f(unsigned short u) {
    return __uint_as_float((unsigned)u << 16);
}

__device__ __forceinline__ unsigned pack2(float a, float b) {
    return (unsigned)f2bf(a) | ((unsigned)f2bf(b) << 16);
}

// async global->LDS, 16B per lane; lds dst is wave-uniform base (HW adds lane*16)
__device__ __forceinline__ void gload16(unsigned short* lds, const unsigned short* g) {
    __builtin_amdgcn_global_load_lds(
        (const __attribute__((address_space(1))) unsigned int*)g,
        (__attribute__((address_space(3))) unsigned int*)lds,
        16, 0, 0);
}

// square 8 packed bf16 (exact f32 square, RNE-lite repack)
__device__ __forceinline__ short8 sq8(short8 w) {
    union { short8 s; unsigned u[4]; } in, out;
    in.s = w;
    #pragma unroll
    for (int i = 0; i < 4; i++) {
        unsigned p = in.u[i];
        float lo = __uint_as_float(p << 16);
        float hi = __uint_as_float(p & 0xffff0000u);
        unsigned lu = __float_as_uint(lo * lo);
        unsigned hu = __float_as_uint(hi * hi);
        out.u[i] = ((lu + 0x8000u) >> 16) | ((hu + 0x8000u) & 0xffff0000u);
    }
    return out.s;
}

// ---------------- fused prep: blocks [0,4096) per-row A-operands,
//                  blocks [4096,5120) W bf16 conversion ----------------------
__global__ __launch_bounds__(256) void prep_all(
        const float* __restrict__ F, const float* __restrict__ CV,
        const float* __restrict__ W, const int* __restrict__ labels,
        const float* __restrict__ ratio_p,
        unsigned short* __restrict__ Fb, unsigned short* __restrict__ Ub,
        unsigned short* __restrict__ Vb, unsigned short* __restrict__ Wb,
        float* __restrict__ t3c) {
    int bid = blockIdx.x;
    if (bid >= N_ROWS) {
        int t = (bid - N_ROWS) * 256 + threadIdx.x;
        int a8 = t * 8;
        int c = a8 >> 11;
        int a = a8 & (A_DIM - 1);
        float4 w0 = make_float4(0.f, 0.f, 0.f, 0.f);
        float4 w1 = make_float4(0.f, 0.f, 0.f, 0.f);
        if (c < C_CLS) {
            w0 = *(const float4*)(W + (size_t)c * A_DIM + a);
            w1 = *(const float4*)(W + (size_t)c * A_DIM + a + 4);
        }
        uint4 pw;
        pw.x = pack2(w0.x, w0.y);  pw.y = pack2(w0.z, w0.w);
        pw.z = pack2(w1.x, w1.y);  pw.w = pack2(w1.z, w1.w);
        *(uint4*)(Wb + (size_t)a8) = pw;
        return;
    }
    int n = bid;
    int y = labels[n];
    float ratio = ratio_p[0];
    float hr = 0.5f * ratio;
    const float* frow  = F  + (size_t)n * A_DIM;
    const float* cvrow = CV + (size_t)n * A_DIM;
    const float* wyrow = W  + (size_t)y * A_DIM;
    size_t obase = (size_t)n * A_DIM;

    int a = threadIdx.x * 8;
    float4 f0  = *(const float4*)(frow + a);
    float4 f1  = *(const float4*)(frow + a + 4);
    float4 c0  = *(const float4*)(cvrow + a);
    float4 c1  = *(const float4*)(cvrow + a + 4);
    float4 y0  = *(const float4*)(wyrow + a);
    float4 y1  = *(const float4*)(wyrow + a + 4);

    float s = y0.x*y0.x*c0.x + y0.y*y0.y*c0.y + y0.z*y0.z*c0.z + y0.w*y0.w*c0.w
            + y1.x*y1.x*c1.x + y1.y*y1.y*c1.y + y1.z*y1.z*c1.z + y1.w*y1.w*c1.w;

    uint4 pf, pu, pv;
    pf.x = pack2(f0.x, f0.y);  pf.y = pack2(f0.z, f0.w);
    pf.z = pack2(f1.x, f1.y);  pf.w = pack2(f1.z, f1.w);
    pu.x = pack2(f0.x - ratio*c0.x*y0.x, f0.y - ratio*c0.y*y0.y);
    pu.y = pack2(f0.z - ratio*c0.z*y0.z, f0.w - ratio*c0.w*y0.w);
    pu.z = pack2(f1.x - ratio*c1.x*y1.x, f1.y - ratio*c1.y*y1.y);
    pu.w = pack2(f1.z - ratio*c1.z*y1.z, f1.w - ratio*c1.w*y1.w);
    pv.x = pack2(hr*c0.x, hr*c0.y);  pv.y = pack2(hr*c0.z, hr*c0.w);
    pv.z = pack2(hr*c1.x, hr*c1.y);  pv.w = pack2(hr*c1.z, hr*c1.w);
    *(uint4*)(Fb + obase + a) = pf;
    *(uint4*)(Ub + obase + a) = pu;
    *(uint4*)(Vb + obase + a) = pv;

    for (int off = 32; off; off >>= 1) s += __shfl_down(s, off);
    __shared__ float wsum[4];
    int lane = threadIdx.x & 63, wid = threadIdx.x >> 6;
    if (lane == 0) wsum[wid] = s;
    __syncthreads();
    if (threadIdx.x == 0)
        t3c[n] = hr * (wsum[0] + wsum[1] + wsum[2] + wsum[3]);
}

// ---------------- fused triple-GEMM: logits(f32) + aug(bf16) ----------------
// Depth-2 counted-vmcnt pipeline (T4): loads for tile t+1 stay in flight
// across the barriers; never drain vmcnt to 0 in steady state.
#define BM 128
#define BN 64
#define BK 32
#define TILE_A (BM * BK)              // 4096 ushorts (8KB)
#define TILE_B (BN * BK)              // 2048 ushorts (4KB)
#define BUF_USH (3 * TILE_A + TILE_B) // 14336 ushorts = 28KB per buffer
#define NT (A_DIM / BK)               // 64 K-steps

__global__ __launch_bounds__(256, 2) void gemm_fused(
        const unsigned short* __restrict__ Fb, const unsigned short* __restrict__ Ub,
        const unsigned short* __restrict__ Vb, const unsigned short* __restrict__ Wb,
        const float* __restrict__ t3c, const float* __restrict__ bias,
        float* __restrict__ out_logits, unsigned short* __restrict__ aug) {
    __shared__ unsigned short lds[2 * BUF_USH];   // 56 KiB double-buffered

    // grid 512 = 32 bm x 16 bn; XCD x owns bn pair {2x,2x+1} (B L2-resident)
    int bid = blockIdx.x;
    int xcd = bid & 7, idx = bid >> 3;            // idx in [0,64)
    int bn = (xcd << 1) | (idx & 1);              // [0,16)
    int bm = idx >> 1;                            // [0,32)

    int tid = threadIdx.x;
    int lane = tid & 63, wid = tid >> 6;
    int wm = wid >> 1, wn = wid & 1;              // 2x2 waves; wave tile 64x32

    // staging: per issue, wave covers 16 rows x 32 cols (1KB)
    int srow = lane >> 2;                                   // 0..15
    int scs  = ((lane & 3) * 8) ^ (((srow >> 1) & 3) << 3); // swizzled col
    int r0 = wid * 16 + srow;
    size_t gA0 = (size_t)(bm * BM + r0) * A_DIM + scs;
    size_t gB0 = (size_t)(bn * BN + r0) * A_DIM + scs;
    const size_t gStep = (size_t)64 * A_DIM;
    int d0 = wid * 512;           // LDS chunk (ushorts), rows [0,64)
    int d1 = 2048 + wid * 512;    // rows [64,128) for A tiles

    // fragment read addressing (same XOR -> conflict-free, verified 0 in R4)
    int fr = lane & 15;
    int kof = ((lane >> 4) * 8) ^ (((fr >> 1) & 3) << 3);
    int aoff = fr * BK + kof;

    f32x4 accL[4][2] = {};
    f32x4 accA[4][2] = {};

#define STAGE(buf, ka, kb)                                        \
    do {                                                          \
        unsigned short* _b = (buf);                               \
        gload16(_b + 0*TILE_A + d0, Fb + (ka));                   \
        gload16(_b + 0*TILE_A + d1, Fb + (ka) + gStep);           \
        gload16(_b + 1*TILE_A + d0, Ub + (ka));                   \
        gload16(_b + 1*TILE_A + d1, Ub + (ka) + gStep);           \
        gload16(_b + 2*TILE_A + d0, Vb + (ka));                   \
        gload16(_b + 2*TILE_A + d1, Vb + (ka) + gStep);           \
        gload16(_b + 3*TILE_A + d0, Wb + (kb));                   \
    } while (0)

    // prologue: stage t0 -> buf0, t1 -> buf1; wait t0 only (t1 stays in flight)
    STAGE(lds,           gA0,      gB0);
    STAGE(lds + BUF_USH, gA0 + BK, gB0 + BK);
    asm volatile("s_waitcnt vmcnt(7)" ::: "memory");
    __builtin_amdgcn_s_barrier();
    __builtin_amdgcn_sched_barrier(0);

    for (int t = 0; t < NT; t++) {
        unsigned short* cbuf = lds + (t & 1) * BUF_USH;

        // (1) fragment ds_reads for tile t
        short8 aF[4], aU[4], aV[4], bWf[2];
        #pragma unroll
        for (int m = 0; m < 4; m++) {
            int off = wm * 2048 + m * 512 + aoff;
            aF[m] = *(const short8*)(cbuf + 0*TILE_A + off);
            aU[m] = *(const short8*)(cbuf + 1*TILE_A + off);
            aV[m] = *(const short8*)(cbuf + 2*TILE_A + off);
        }
        #pragma unroll
        for (int n = 0; n < 2; n++) {
            int off = wn * 1024 + n * 512 + aoff;
            bWf[n] = *(const short8*)(cbuf + 3*TILE_A + off);
        }

        // (2) reads complete -> barrier licenses overwrite of cbuf
        asm volatile("s_waitcnt lgkmcnt(0)" ::: "memory");
        __builtin_amdgcn_s_barrier();
        __builtin_amdgcn_sched_barrier(0);

        // (3) prefetch tile t+2 into cbuf (the buffer just consumed)
        if (t + 2 < NT) {
            size_t ka = gA0 + (size_t)(t + 2) * BK;
            size_t kb = gB0 + (size_t)(t + 2) * BK;
            STAGE(cbuf, ka, kb);
        }

        // (4) derive W^2 frags in registers + MFMA
        short8 bW2f[2];
        #pragma unroll
        for (int n = 0; n < 2; n++) bW2f[n] = sq8(bWf[n]);
        #pragma unroll
        for (int m = 0; m < 4; m++)
            #pragma unroll
            for (int n = 0; n < 2; n++) {
                accL[m][n] = __builtin_amdgcn_mfma_f32_16x16x32_bf16(aF[m], bWf[n],  accL[m][n], 0, 0, 0);
                accA[m][n] = __builtin_amdgcn_mfma_f32_16x16x32_bf16(aU[m], bWf[n],  accA[m][n], 0, 0, 0);
                accA[m][n] = __builtin_amdgcn_mfma_f32_16x16x32_bf16(aV[m], bW2f[n], accA[m][n], 0, 0, 0);
            }

        // (5)+(6) wait for tile t+1's loads (t+2 stays in flight), then sync
        if (t + 1 < NT) {
            if (t + 2 < NT) {
                asm volatile("s_waitcnt vmcnt(7)" ::: "memory");
            } else {
                asm volatile("s_waitcnt vmcnt(0)" ::: "memory");
            }
            __builtin_amdgcn_s_barrier();
            __builtin_amdgcn_sched_barrier(0);
        }
    }
#undef STAGE

    // epilogue: logits f32 -> d_out+1; aug bf16 -> ws
    #pragma unroll
    for (int n = 0; n < 2; n++) {
        int col = bn * BN + wn * 32 + n * 16 + fr;
        if (col < C_CLS) {
            float bv = bias[col];
            #pragma unroll
            for (int m = 0; m < 4; m++) {
                int rbase = bm * BM + wm * 64 + m * 16 + (lane >> 4) * 4;
                #pragma unroll
                for (int j = 0; j < 4; j++) {
                    int row = rbase + j;
                    out_logits[(size_t)row * C_CLS + col] = accL[m][n][j] + bv;
                    aug[(size_t)row * C_PAD + col] = f2bf(accA[m][n][j] + bv + t3c[row]);
                }
            }
        }
    }
}

// ---------------- per-row softmax NLL (bf16 aug) ----------------------------
__global__ __launch_bounds__(256) void softmax_nll(const unsigned short* __restrict__ aug,
                                                   const int* __restrict__ labels,
                                                   float* __restrict__ nll) {
    int n = blockIdx.x;
    const unsigned short* row = aug + (size_t)n * C_PAD;
    int tid = threadIdx.x;
    int lane = tid & 63, wid = tid >> 6;
    __shared__ float sm[4], ss[4];

    float v[8];
    bool act = tid < (C_CLS / 8);    // 125 active threads, 8 elems each
    float mx = -1e30f;
    if (act) {
        short8 r8 = *(const short8*)(row + tid * 8);
        #pragma unroll
        for (int j = 0; j < 8; j++) {
            v[j] = bf2f((unsigned short)r8[j]);
            mx = fmaxf(mx, v[j]);
        }
    }
    for (int off = 32; off; off >>= 1) mx = fmaxf(mx, __shfl_down(mx, off));
    if (lane == 0) sm[wid] = mx;
    __syncthreads();
    mx = fmaxf(fmaxf(sm[0], sm[1]), fmaxf(sm[2], sm[3]));

    float s = 0.f;
    if (act) {
        #pragma unroll
        for (int j = 0; j < 8; j++) s += __expf(v[j] - mx);
    }
    for (int off = 32; off; off >>= 1) s += __shfl_down(s, off);
    if (lane == 0) ss[wid] = s;
    __syncthreads();
    if (tid == 0) {
        float tot = ss[0] + ss[1] + ss[2] + ss[3];
        nll[n] = logf(tot) + mx - bf2f(row[labels[n]]);
    }
}

__global__ __launch_bounds__(256) void final_reduce(const float* __restrict__ nll,
                                                    float* __restrict__ out_loss) {
    float s = 0.f;
    for (int i = threadIdx.x; i < N_ROWS; i += 256) s += nll[i];
    for (int off = 32; off; off >>= 1) s += __shfl_down(s, off);
    __shared__ float ss[4];
    int lane = threadIdx.x & 63, wid = threadIdx.x >> 6;
    if (lane == 0) ss[wid] = s;
    __syncthreads();
    if (threadIdx.x == 0)
        out_loss[0] = (ss[0] + ss[1] + ss[2] + ss[3]) / (float)N_ROWS;
}

// ---------------- launch -----------------------------------------------------
extern "C" void kernel_launch(void* const* d_in, const int* in_sizes, int n_in,
                              void* d_out, int out_size, void* d_ws, size_t ws_size,
                              hipStream_t stream) {
    const float* features = (const float*)d_in[0];
    const int*   labels   = (const int*)d_in[1];
    const float* cv       = (const float*)d_in[2];
    const float* ratio    = (const float*)d_in[3];
    const float* weight   = (const float*)d_in[4];
    const float* bias     = (const float*)d_in[5];
    float* out = (float*)d_out;

    char* p = (char*)d_ws;
    unsigned short* Wb  = (unsigned short*)p; p += (size_t)C_PAD * A_DIM * 2;
    unsigned short* Fb  = (unsigned short*)p; p += (size_t)N_ROWS * A_DIM * 2;
    unsigned short* Ub  = (unsigned short*)p; p += (size_t)N_ROWS * A_DIM * 2;
    unsigned short* Vb  = (unsigned short*)p; p += (size_t)N_ROWS * A_DIM * 2;
    float* t3c = (float*)p; p += (size_t)N_ROWS * 4;
    unsigned short* aug = (unsigned short*)p; p += (size_t)N_ROWS * C_PAD * 2;
    float* nllb = (float*)p; p += (size_t)N_ROWS * 4;

    int wprep_blocks = (C_PAD * A_DIM / 8) / 256;  // 1024
    prep_all<<<N_ROWS + wprep_blocks, 256, 0, stream>>>(
        features, cv, weight, labels, ratio, Fb, Ub, Vb, Wb, t3c);
    gemm_fused<<<(N_ROWS / BM) * (C_PAD / BN), 256, 0, stream>>>(
        Fb, Ub, Vb, Wb, t3c, bias, out + 1, aug);
    softmax_nll<<<N_ROWS, 256, 0, stream>>>(aug, labels, nllb);
    final_reduce<<<1, 256, 0, stream>>>(nllb, out);
}